// Round 1
// baseline (622.878 us; speedup 1.0000x reference)
//
#include <hip/hip_runtime.h>
#include <hip/hip_bf16.h>

#define S_LEN 2048
#define NH 32
#define D_DIM 128
#define LAST_Q 64
#define SCALE_F 0.08838834764831845f

typedef __attribute__((ext_vector_type(8))) short bf16x8;
typedef __attribute__((ext_vector_type(4))) float f32x4;
typedef unsigned long long u64;
typedef unsigned int u32;
typedef unsigned short u16;

static __device__ __forceinline__ u16 f32_bf16(float f) {
  u32 u = __float_as_uint(f);
  u32 r = (u + 0x7FFFu + ((u >> 16) & 1u)) >> 16;
  return (u16)r;
}

// ---------------- Stage 1a: est scores (f32, causal-masked, scaled) ----------------
// grid (32 colchunks, 32 heads), 256 threads. scores[h][64][2048] into d_out scratch.
__global__ __launch_bounds__(256) void est_kernel(const float* __restrict__ q,
                                                  const float* __restrict__ k,
                                                  float* __restrict__ scores) {
  int cc = blockIdx.x;
  int h = blockIdx.y;
  int tid = threadIdx.x;
  int ty = tid >> 4, tx = tid & 15;
  __shared__ float Qs[64][36];
  __shared__ float Ks[64][36];
  float acc[4][4];
#pragma unroll
  for (int i = 0; i < 4; ++i)
#pragma unroll
    for (int j = 0; j < 4; ++j) acc[i][j] = 0.f;
  const float* qbase = q + ((size_t)h * S_LEN + (S_LEN - LAST_Q)) * D_DIM;
  const float* kbase = k + ((size_t)h * S_LEN + cc * 64) * D_DIM;
  for (int dc = 0; dc < 4; ++dc) {
    __syncthreads();
    for (int i = tid; i < 512; i += 256) {
      int r = i >> 3, s = i & 7;
      float4 a = *(const float4*)(qbase + (size_t)r * D_DIM + dc * 32 + s * 4);
      *(float4*)&Qs[r][s * 4] = a;
      float4 b = *(const float4*)(kbase + (size_t)r * D_DIM + dc * 32 + s * 4);
      *(float4*)&Ks[r][s * 4] = b;
    }
    __syncthreads();
#pragma unroll
    for (int d4 = 0; d4 < 8; ++d4) {
      float4 qv[4], kv[4];
#pragma unroll
      for (int i = 0; i < 4; ++i) qv[i] = *(const float4*)&Qs[ty + 16 * i][d4 * 4];
#pragma unroll
      for (int j = 0; j < 4; ++j) kv[j] = *(const float4*)&Ks[tx + 16 * j][d4 * 4];
#pragma unroll
      for (int i = 0; i < 4; ++i)
#pragma unroll
        for (int j = 0; j < 4; ++j)
          acc[i][j] += qv[i].x * kv[j].x + qv[i].y * kv[j].y + qv[i].z * kv[j].z + qv[i].w * kv[j].w;
    }
  }
#pragma unroll
  for (int i = 0; i < 4; ++i) {
    int rl = ty + 16 * i;
    int rg = (S_LEN - LAST_Q) + rl;
#pragma unroll
    for (int j = 0; j < 4; ++j) {
      int cg = cc * 64 + tx + 16 * j;
      float vv = (cg <= rg) ? acc[i][j] * SCALE_F : -1e30f;
      scores[((size_t)h * LAST_Q + rl) * S_LEN + cg] = vv;
    }
  }
}

// ---------------- Stage 1b: softmax rows + vertical/slash accumulation ----------------
// grid 32 (head), 256 threads.
__global__ __launch_bounds__(256) void soft_acc_kernel(const float* __restrict__ scores,
                                                       float* __restrict__ vert,
                                                       float* __restrict__ slash) {
  int h = blockIdx.x;
  int tid = threadIdx.x;
  __shared__ float vs[2048];
  __shared__ float ss[2048];
  __shared__ float row[2048];
  __shared__ float red[256];
  for (int i = tid; i < 2048; i += 256) { vs[i] = 0.f; ss[i] = 0.f; }
  for (int r = 0; r < 64; ++r) {
    __syncthreads();
    const float* sp = scores + ((size_t)h * LAST_Q + r) * S_LEN;
    float pm = -1e30f;
    for (int i = tid; i < 2048; i += 256) { float x = sp[i]; row[i] = x; pm = fmaxf(pm, x); }
    red[tid] = pm; __syncthreads();
    for (int s2 = 128; s2 > 0; s2 >>= 1) { if (tid < s2) red[tid] = fmaxf(red[tid], red[tid + s2]); __syncthreads(); }
    float m = red[0]; __syncthreads();
    float psum = 0.f;
    for (int i = tid; i < 2048; i += 256) { float e = __expf(row[i] - m); row[i] = e; psum += e; }
    red[tid] = psum; __syncthreads();
    for (int s2 = 128; s2 > 0; s2 >>= 1) { if (tid < s2) red[tid] += red[tid + s2]; __syncthreads(); }
    float inv = 1.f / red[0];
    int rg = (S_LEN - LAST_Q) + r;
    for (int i = tid; i < 2048; i += 256) {
      float p = row[i] * inv;
      vs[i] += p;
      int d = rg - i;
      if (d >= 0) ss[d] += p;
    }
  }
  __syncthreads();
  for (int i = tid; i < 2048; i += 256) {
    vert[(size_t)h * 2048 + i] = vs[i];
    slash[(size_t)h * 2048 + i] = ss[i];
  }
}

// ---------------- Stage 1c: top-k -> bitmasks (radix select, stable tie-break) ----------------
// grid (32 heads, 2 which), 256 threads.
__global__ __launch_bounds__(256) void topk_kernel(const float* __restrict__ vert,
                                                   const float* __restrict__ slash,
                                                   u64* __restrict__ vbits,
                                                   u64* __restrict__ sbits) {
  int h = blockIdx.x;
  int which = blockIdx.y;
  const float* src = which ? (slash + (size_t)h * 2048) : (vert + (size_t)h * 2048);
  u64* dst = which ? (sbits + h * 32) : (vbits + h * 32);
  int K = which ? 512 : 256;
  int ninf = which ? 64 : 4;
  int tid = threadIdx.x;
  __shared__ u32 keys[2048];
  __shared__ u32 hist[256];
  __shared__ u32 sh_pref, sh_kth;
  __shared__ u64 mb[32];
  for (int i = tid; i < 2048; i += 256)
    keys[i] = (i < ninf) ? 0x7F800000u : __float_as_uint(src[i]);
  __syncthreads();
  u32 prefix = 0;
  int kth = K;
  for (int shift = 24; shift >= 0; shift -= 8) {
    hist[tid] = 0;
    __syncthreads();
    int hb = shift + 8;
    for (int i = tid; i < 2048; i += 256) {
      u32 kk = keys[i];
      if (hb == 32 || (kk >> hb) == (prefix >> hb))
        atomicAdd(&hist[(kk >> shift) & 255], 1u);
    }
    __syncthreads();
    if (tid == 0) {
      int accum = 0;
      for (int b = 255; b >= 0; --b) {
        int c = (int)hist[b];
        if (accum + c >= kth) {
          sh_kth = (u32)(kth - accum);
          sh_pref = prefix | ((u32)b << shift);
          break;
        }
        accum += c;
      }
    }
    __syncthreads();
    prefix = sh_pref;
    kth = (int)sh_kth;
    __syncthreads();
  }
  u32 t = prefix;
  if (tid < 32) mb[tid] = 0ull;
  __syncthreads();
  for (int i = tid; i < 2048; i += 256)
    if (keys[i] > t) atomicOr(&mb[i >> 6], 1ull << (i & 63));
  __syncthreads();
  if (tid == 0) {
    int need = kth;
    for (int i = 0; i < 2048 && need > 0; ++i)
      if (keys[i] == t) { mb[i >> 6] |= 1ull << (i & 63); --need; }
  }
  __syncthreads();
  if (tid < 32) dst[tid] = mb[tid];
}

// ---------------- Stage 2: masked causal flash attention (bf16 MFMA) ----------------
// grid 1024 blocks, 256 threads (4 waves x 16 q-rows each).
__global__ __launch_bounds__(256) void attn_kernel(const float* __restrict__ q,
                                                   const float* __restrict__ kk,
                                                   const float* __restrict__ vv,
                                                   const u64* __restrict__ vbits,
                                                   const u64* __restrict__ sbits,
                                                   float* __restrict__ out) {
  int bid = blockIdx.x;
  int logical = (bid & 7) * 128 + (bid >> 3);  // XCD-grouping: 4 heads per XCD
  int h = logical >> 5;
  int qt = 31 - (logical & 31);                // heavy q-tiles dispatched first
  int tid = threadIdx.x;
  int wave = tid >> 6, lane = tid & 63;
  int grp = lane >> 4, ln = lane & 15;

  __shared__ u16 Ks[64][136];
  __shared__ u16 Vt[128][72];
  __shared__ u16 Ps[4][16][72];
  __shared__ u64 vm[32], sm[32];

  if (tid < 32) vm[tid] = vbits[h * 32 + tid];
  else if (tid < 64) sm[tid - 32] = sbits[h * 32 + (tid - 32)];

  int q0 = qt * 64 + wave * 16;
  // Q fragments (A-layout: lane -> row ln, k-offset grp*8 within 32-wide kstep)
  bf16x8 qf[4];
  const float* qrow = q + ((size_t)h * S_LEN + q0 + ln) * D_DIM;
#pragma unroll
  for (int ks = 0; ks < 4; ++ks) {
    const float* p = qrow + ks * 32 + grp * 8;
    float4 a = *(const float4*)p;
    float4 b = *(const float4*)(p + 4);
    bf16x8 f;
    f[0] = (short)f32_bf16(a.x); f[1] = (short)f32_bf16(a.y);
    f[2] = (short)f32_bf16(a.z); f[3] = (short)f32_bf16(a.w);
    f[4] = (short)f32_bf16(b.x); f[5] = (short)f32_bf16(b.y);
    f[6] = (short)f32_bf16(b.z); f[7] = (short)f32_bf16(b.w);
    qf[ks] = f;
  }
  f32x4 of[8];
#pragma unroll
  for (int i = 0; i < 8; ++i) of[i] = (f32x4){0.f, 0.f, 0.f, 0.f};
  float mr[4] = {-1e30f, -1e30f, -1e30f, -1e30f};
  float ls[4] = {0.f, 0.f, 0.f, 0.f};

  const float* kb = kk + (size_t)h * S_LEN * D_DIM;
  const float* vb = vv + (size_t)h * S_LEN * D_DIM;
  int ntiles = qt + 1;

  for (int t = 0; t < ntiles; ++t) {
    int c0 = t * 64;
    __syncthreads();
    // stage K tile -> Ks (bf16), 16 floats per (thread, iter)
    for (int i = tid; i < 512; i += 256) {
      int r = i >> 3, s = i & 7;
      const float* src = kb + (size_t)(c0 + r) * D_DIM + s * 16;
      bf16x8 t0, t1;
      float4 f0 = *(const float4*)(src);
      float4 f1 = *(const float4*)(src + 4);
      float4 f2 = *(const float4*)(src + 8);
      float4 f3 = *(const float4*)(src + 12);
      t0[0] = (short)f32_bf16(f0.x); t0[1] = (short)f32_bf16(f0.y);
      t0[2] = (short)f32_bf16(f0.z); t0[3] = (short)f32_bf16(f0.w);
      t0[4] = (short)f32_bf16(f1.x); t0[5] = (short)f32_bf16(f1.y);
      t0[6] = (short)f32_bf16(f1.z); t0[7] = (short)f32_bf16(f1.w);
      t1[0] = (short)f32_bf16(f2.x); t1[1] = (short)f32_bf16(f2.y);
      t1[2] = (short)f32_bf16(f2.z); t1[3] = (short)f32_bf16(f2.w);
      t1[4] = (short)f32_bf16(f3.x); t1[5] = (short)f32_bf16(f3.y);
      t1[6] = (short)f32_bf16(f3.z); t1[7] = (short)f32_bf16(f3.w);
      *(bf16x8*)&Ks[r][s * 16] = t0;
      *(bf16x8*)&Ks[r][s * 16 + 8] = t1;
    }
    // stage V tile transposed -> Vt with XOR block swizzle (cb' = cb ^ ((d>>4)&7))
    for (int i = tid; i < 512; i += 256) {
      int r = i >> 3, s = i & 7;  // r = col c in tile, s = d-seg
      const float* src = vb + (size_t)(c0 + r) * D_DIM + s * 16;
      int cswz_blk = ((r >> 3) ^ s) << 3;
      int cswz = cswz_blk | (r & 7);
#pragma unroll
      for (int x = 0; x < 16; x += 4) {
        float4 f4 = *(const float4*)(src + x);
        int d0 = s * 16 + x;
        Vt[d0][cswz]     = f32_bf16(f4.x);
        Vt[d0 + 1][cswz] = f32_bf16(f4.y);
        Vt[d0 + 2][cswz] = f32_bf16(f4.z);
        Vt[d0 + 3][cswz] = f32_bf16(f4.w);
      }
    }
    __syncthreads();

    // QK^T: 4 col-blocks x 4 ksteps
    f32x4 sfr[4];
#pragma unroll
    for (int nb = 0; nb < 4; ++nb) {
      f32x4 acc = (f32x4){0.f, 0.f, 0.f, 0.f};
#pragma unroll
      for (int ks = 0; ks < 4; ++ks) {
        bf16x8 kf = *(const bf16x8*)&Ks[nb * 16 + ln][ks * 32 + grp * 8];
        acc = __builtin_amdgcn_mfma_f32_16x16x32_bf16(qf[ks], kf, acc, 0, 0, 0);
      }
      int c = c0 + nb * 16 + ln;
      int vbit = (int)((vm[c >> 6] >> (c & 63)) & 1ull);
#pragma unroll
      for (int j = 0; j < 4; ++j) {
        int r = q0 + grp * 4 + j;
        int d = r - c;
        bool keep = false;
        if (d >= 0) keep = vbit || ((sm[d >> 6] >> (d & 63)) & 1ull);
        acc[j] = keep ? acc[j] * SCALE_F : -1e30f;
      }
      sfr[nb] = acc;
    }
    // row max across 4 nb + 16 lanes
    f32x4 tm = sfr[0];
#pragma unroll
    for (int nb = 1; nb < 4; ++nb)
#pragma unroll
      for (int j = 0; j < 4; ++j) tm[j] = fmaxf(tm[j], sfr[nb][j]);
#pragma unroll
    for (int mk = 1; mk <= 8; mk <<= 1)
#pragma unroll
      for (int j = 0; j < 4; ++j) tm[j] = fmaxf(tm[j], __shfl_xor(tm[j], mk, 64));
    // online rescale
    float ex[4];
#pragma unroll
    for (int j = 0; j < 4; ++j) {
      float mn = fmaxf(mr[j], tm[j]);
      ex[j] = __expf(mr[j] - mn);
      mr[j] = mn;
      ls[j] *= ex[j];
    }
#pragma unroll
    for (int db = 0; db < 8; ++db)
#pragma unroll
      for (int j = 0; j < 4; ++j) of[db][j] *= ex[j];
    // p = exp(s-m), row sums, stash P (bf16) in LDS
    float rs[4] = {0.f, 0.f, 0.f, 0.f};
#pragma unroll
    for (int nb = 0; nb < 4; ++nb)
#pragma unroll
      for (int j = 0; j < 4; ++j) {
        float p = __expf(sfr[nb][j] - mr[j]);
        rs[j] += p;
        Ps[wave][grp * 4 + j][nb * 16 + ln] = f32_bf16(p);
      }
#pragma unroll
    for (int mk = 1; mk <= 8; mk <<= 1)
#pragma unroll
      for (int j = 0; j < 4; ++j) rs[j] += __shfl_xor(rs[j], mk, 64);
#pragma unroll
    for (int j = 0; j < 4; ++j) ls[j] += rs[j];
    // PV: A = P rows, B = V columns via swizzled Vt
#pragma unroll
    for (int ks = 0; ks < 2; ++ks) {
      bf16x8 pa = *(const bf16x8*)&Ps[wave][ln][ks * 32 + grp * 8];
#pragma unroll
      for (int db = 0; db < 8; ++db) {
        int d = db * 16 + ln;
        int cb = ((ks * 4 + grp) ^ db) << 3;
        bf16x8 vf = *(const bf16x8*)&Vt[d][cb];
        of[db] = __builtin_amdgcn_mfma_f32_16x16x32_bf16(pa, vf, of[db], 0, 0, 0);
      }
    }
  }
  // epilogue
  float inv[4];
#pragma unroll
  for (int j = 0; j < 4; ++j) inv[j] = 1.f / ls[j];
  float* ob = out + ((size_t)h * S_LEN + q0) * D_DIM;
#pragma unroll
  for (int db = 0; db < 8; ++db)
#pragma unroll
    for (int j = 0; j < 4; ++j)
      ob[(size_t)(grp * 4 + j) * D_DIM + db * 16 + ln] = of[db][j] * inv[j];
}

extern "C" void kernel_launch(void* const* d_in, const int* in_sizes, int n_in,
                              void* d_out, int out_size, void* d_ws, size_t ws_size,
                              hipStream_t stream) {
  const float* q = (const float*)d_in[0];
  const float* k = (const float*)d_in[1];
  const float* v = (const float*)d_in[2];
  float* out = (float*)d_out;
  // d_out doubles as scratch for stage 1 (fully overwritten by attn_kernel).
  float* scores = out;                  // 32*64*2048 = 4,194,304 floats
  float* vert = out + 4194304;          // 32*2048
  float* slash = vert + 65536;          // 32*2048
  u64* vbits = (u64*)d_ws;              // 32 heads * 32 u64
  u64* sbits = vbits + 1024;

  est_kernel<<<dim3(32, 32), 256, 0, stream>>>(q, k, scores);
  soft_acc_kernel<<<32, 256, 0, stream>>>(scores, vert, slash);
  topk_kernel<<<dim3(32, 2), 256, 0, stream>>>(vert, slash, vbits, sbits);
  attn_kernel<<<1024, 256, 0, stream>>>(q, k, v, vbits, sbits, out);
}

// Round 2
// 211.885 us; speedup vs baseline: 2.9397x; 2.9397x over previous
//
#include <hip/hip_runtime.h>
#include <hip/hip_bf16.h>

#define S_LEN 2048
#define NH 32
#define D_DIM 128
#define LAST_Q 64
#define SCALE_F 0.08838834764831845f

typedef __attribute__((ext_vector_type(8))) short bf16x8;
typedef __attribute__((ext_vector_type(4))) float f32x4;
typedef unsigned long long u64;
typedef unsigned int u32;
typedef unsigned short u16;

static __device__ __forceinline__ u16 f32_bf16(float f) {
  u32 u = __float_as_uint(f);
  u32 r = (u + 0x7FFFu + ((u >> 16) & 1u)) >> 16;
  return (u16)r;
}

// ---------------- Stage 1a: est scores (f32, causal-masked, scaled) ----------------
__global__ __launch_bounds__(256) void est_kernel(const float* __restrict__ q,
                                                  const float* __restrict__ k,
                                                  float* __restrict__ scores) {
  int cc = blockIdx.x;
  int h = blockIdx.y;
  int tid = threadIdx.x;
  int ty = tid >> 4, tx = tid & 15;
  __shared__ float Qs[64][36];
  __shared__ float Ks[64][36];
  float acc[4][4];
#pragma unroll
  for (int i = 0; i < 4; ++i)
#pragma unroll
    for (int j = 0; j < 4; ++j) acc[i][j] = 0.f;
  const float* qbase = q + ((size_t)h * S_LEN + (S_LEN - LAST_Q)) * D_DIM;
  const float* kbase = k + ((size_t)h * S_LEN + cc * 64) * D_DIM;
  for (int dc = 0; dc < 4; ++dc) {
    __syncthreads();
    for (int i = tid; i < 512; i += 256) {
      int r = i >> 3, s = i & 7;
      float4 a = *(const float4*)(qbase + (size_t)r * D_DIM + dc * 32 + s * 4);
      *(float4*)&Qs[r][s * 4] = a;
      float4 b = *(const float4*)(kbase + (size_t)r * D_DIM + dc * 32 + s * 4);
      *(float4*)&Ks[r][s * 4] = b;
    }
    __syncthreads();
#pragma unroll
    for (int d4 = 0; d4 < 8; ++d4) {
      float4 qv[4], kv[4];
#pragma unroll
      for (int i = 0; i < 4; ++i) qv[i] = *(const float4*)&Qs[ty + 16 * i][d4 * 4];
#pragma unroll
      for (int j = 0; j < 4; ++j) kv[j] = *(const float4*)&Ks[tx + 16 * j][d4 * 4];
#pragma unroll
      for (int i = 0; i < 4; ++i)
#pragma unroll
        for (int j = 0; j < 4; ++j)
          acc[i][j] += qv[i].x * kv[j].x + qv[i].y * kv[j].y + qv[i].z * kv[j].z + qv[i].w * kv[j].w;
    }
  }
#pragma unroll
  for (int i = 0; i < 4; ++i) {
    int rl = ty + 16 * i;
    int rg = (S_LEN - LAST_Q) + rl;
#pragma unroll
    for (int j = 0; j < 4; ++j) {
      int cg = cc * 64 + tx + 16 * j;
      float vv = (cg <= rg) ? acc[i][j] * SCALE_F : -1e30f;
      scores[((size_t)h * LAST_Q + rl) * S_LEN + cg] = vv;
    }
  }
}

// ---------------- Stage 1b: softmax partials (parallel over rowgroups) ----------------
// grid (32 h, 8 rg), 256 threads. part[(h*8+rg)][0..2047]=vs, [2048..4095]=ss
__global__ __launch_bounds__(256) void soft_partial_kernel(const float* __restrict__ scores,
                                                           float* __restrict__ part) {
  int h = blockIdx.x, rg = blockIdx.y;
  int tid = threadIdx.x;
  int wave = tid >> 6, lane = tid & 63;
  __shared__ float vs[2048];
  __shared__ float ss[2048];
  __shared__ float red[4];
  int i0 = tid * 8;
#pragma unroll
  for (int e = 0; e < 8; ++e) { vs[i0 + e] = 0.f; ss[i0 + e] = 0.f; }
  for (int rr = 0; rr < 8; ++rr) {
    int r = rg * 8 + rr;
    const float* sp = scores + ((size_t)h * LAST_Q + r) * S_LEN;
    float4 a = *(const float4*)(sp + i0);
    float4 b = *(const float4*)(sp + i0 + 4);
    float x[8] = {a.x, a.y, a.z, a.w, b.x, b.y, b.z, b.w};
    float wm = -1e30f;
#pragma unroll
    for (int e = 0; e < 8; ++e) wm = fmaxf(wm, x[e]);
#pragma unroll
    for (int mk = 1; mk < 64; mk <<= 1) wm = fmaxf(wm, __shfl_xor(wm, mk, 64));
    __syncthreads();
    if (lane == 0) red[wave] = wm;
    __syncthreads();
    float m = fmaxf(fmaxf(red[0], red[1]), fmaxf(red[2], red[3]));
    float psum = 0.f;
#pragma unroll
    for (int e = 0; e < 8; ++e) { x[e] = __expf(x[e] - m); psum += x[e]; }
#pragma unroll
    for (int mk = 1; mk < 64; mk <<= 1) psum += __shfl_xor(psum, mk, 64);
    __syncthreads();
    if (lane == 0) red[wave] = psum;
    __syncthreads();
    float inv = 1.f / (red[0] + red[1] + red[2] + red[3]);
    int rgl = (S_LEN - LAST_Q) + r;
#pragma unroll
    for (int e = 0; e < 8; ++e) {
      float p = x[e] * inv;
      int i = i0 + e;
      vs[i] += p;
      int d = rgl - i;
      if (d >= 0) ss[d] += p;
    }
  }
  __syncthreads();
  float* pb = part + ((size_t)(h * 8 + rg)) * 4096;
#pragma unroll
  for (int e = 0; e < 8; ++e) { pb[i0 + e] = vs[i0 + e]; pb[2048 + i0 + e] = ss[i0 + e]; }
}

// ---------------- Stage 1b2: reduce partials ----------------
// grid (32 h, 2 which), 256 threads.
__global__ __launch_bounds__(256) void soft_reduce_kernel(const float* __restrict__ part,
                                                          float* __restrict__ vert,
                                                          float* __restrict__ slash) {
  int h = blockIdx.x, which = blockIdx.y;
  int tid = threadIdx.x;
  float4 s0 = {0, 0, 0, 0}, s1 = {0, 0, 0, 0};
  for (int rg = 0; rg < 8; ++rg) {
    const float* pp = part + ((size_t)(h * 8 + rg)) * 4096 + which * 2048 + tid * 8;
    float4 a = *(const float4*)pp;
    float4 b = *(const float4*)(pp + 4);
    s0.x += a.x; s0.y += a.y; s0.z += a.z; s0.w += a.w;
    s1.x += b.x; s1.y += b.y; s1.z += b.z; s1.w += b.w;
  }
  float* dst = (which ? slash : vert) + (size_t)h * 2048 + tid * 8;
  *(float4*)dst = s0;
  *(float4*)(dst + 4) = s1;
}

// ---------------- Stage 1c: parallel top-k -> bitmasks ----------------
// grid (32 heads, 2 which), 256 threads. Contiguous ownership: thread t owns [8t, 8t+8).
__global__ __launch_bounds__(256) void topk_kernel(const float* __restrict__ vert,
                                                   const float* __restrict__ slash,
                                                   u64* __restrict__ vbits,
                                                   u64* __restrict__ sbits) {
  int h = blockIdx.x;
  int which = blockIdx.y;
  const float* src = which ? (slash + (size_t)h * 2048) : (vert + (size_t)h * 2048);
  u64* dst = which ? (sbits + h * 32) : (vbits + h * 32);
  int K = which ? 512 : 256;
  int ninf = which ? 64 : 4;
  int tid = threadIdx.x;
  __shared__ u32 keys[2048];
  __shared__ u32 hist[256];
  __shared__ u32 sc[256];
  __shared__ u32 sh_pref, sh_kth;
  __shared__ u64 mbw[32];
  int i0 = tid * 8;
#pragma unroll
  for (int e = 0; e < 8; ++e) {
    int i = i0 + e;
    keys[i] = (i < ninf) ? 0x7F800000u : __float_as_uint(src[i]);
  }
  __syncthreads();
  u32 prefix = 0;
  u32 kth = (u32)K;
  for (int shift = 24; shift >= 0; shift -= 8) {
    hist[tid] = 0;
    __syncthreads();
#pragma unroll
    for (int e = 0; e < 8; ++e) {
      u32 kk = keys[i0 + e];
      if (shift == 24 || (kk >> (shift + 8)) == (prefix >> (shift + 8)))
        atomicAdd(&hist[(kk >> shift) & 255], 1u);
    }
    __syncthreads();
    // inclusive suffix-sum over hist -> sc
    sc[tid] = hist[tid];
    __syncthreads();
    for (int off = 1; off < 256; off <<= 1) {
      u32 add = (tid + off < 256) ? sc[tid + off] : 0u;
      __syncthreads();
      sc[tid] += add;
      __syncthreads();
    }
    u32 nxt = (tid == 255) ? 0u : sc[tid + 1];
    if (sc[tid] >= kth && nxt < kth) {
      sh_pref = prefix | ((u32)tid << shift);
      sh_kth = kth - nxt;
    }
    __syncthreads();
    prefix = sh_pref;
    kth = sh_kth;
    __syncthreads();
  }
  u32 t = prefix;
  // stable tie-break: rank ties by index via exclusive scan of per-thread tie counts
  u32 cnt = 0;
#pragma unroll
  for (int e = 0; e < 8; ++e) cnt += (keys[i0 + e] == t) ? 1u : 0u;
  sc[tid] = cnt;
  __syncthreads();
  for (int off = 1; off < 256; off <<= 1) {
    u32 add = (tid >= off) ? sc[tid - off] : 0u;
    __syncthreads();
    sc[tid] += add;
    __syncthreads();
  }
  u32 exc = sc[tid] - cnt;
  unsigned char myb = 0;
  u32 seen = 0;
#pragma unroll
  for (int e = 0; e < 8; ++e) {
    u32 kk = keys[i0 + e];
    bool in = (kk > t) || (kk == t && (exc + seen) < kth);
    if (kk == t) ++seen;
    myb |= (in ? 1u : 0u) << e;
  }
  ((unsigned char*)mbw)[tid] = myb;
  __syncthreads();
  if (tid < 32) dst[tid] = mbw[tid];
}

// ---------------- preconvert K -> bf16 ----------------
__global__ __launch_bounds__(256) void convk_kernel(const float* __restrict__ k,
                                                    u16* __restrict__ kbf) {
  size_t base = ((size_t)blockIdx.x * 256 + threadIdx.x) * 8;
  float4 a = *(const float4*)(k + base);
  float4 b = *(const float4*)(k + base + 4);
  bf16x8 o;
  o[0] = (short)f32_bf16(a.x); o[1] = (short)f32_bf16(a.y);
  o[2] = (short)f32_bf16(a.z); o[3] = (short)f32_bf16(a.w);
  o[4] = (short)f32_bf16(b.x); o[5] = (short)f32_bf16(b.y);
  o[6] = (short)f32_bf16(b.z); o[7] = (short)f32_bf16(b.w);
  *(bf16x8*)(kbf + base) = o;
}

// ---------------- preconvert V -> bf16 transposed vt[h][d][c] ----------------
__global__ __launch_bounds__(256) void convv_kernel(const float* __restrict__ v,
                                                    u16* __restrict__ vtg) {
  int cc = blockIdx.x, h = blockIdx.y;
  int tid = threadIdx.x;
  __shared__ u16 Vb[64][136];
  int c0 = cc * 64;
  for (int i = tid; i < 512; i += 256) {
    int r = i >> 3, s = i & 7;
    const float* srcp = v + ((size_t)(h * S_LEN + c0 + r)) * D_DIM + s * 16;
    float4 f0 = *(const float4*)(srcp);
    float4 f1 = *(const float4*)(srcp + 4);
    float4 f2 = *(const float4*)(srcp + 8);
    float4 f3 = *(const float4*)(srcp + 12);
    bf16x8 t0, t1;
    t0[0] = (short)f32_bf16(f0.x); t0[1] = (short)f32_bf16(f0.y);
    t0[2] = (short)f32_bf16(f0.z); t0[3] = (short)f32_bf16(f0.w);
    t0[4] = (short)f32_bf16(f1.x); t0[5] = (short)f32_bf16(f1.y);
    t0[6] = (short)f32_bf16(f1.z); t0[7] = (short)f32_bf16(f1.w);
    t1[0] = (short)f32_bf16(f2.x); t1[1] = (short)f32_bf16(f2.y);
    t1[2] = (short)f32_bf16(f2.z); t1[3] = (short)f32_bf16(f2.w);
    t1[4] = (short)f32_bf16(f3.x); t1[5] = (short)f32_bf16(f3.y);
    t1[6] = (short)f32_bf16(f3.z); t1[7] = (short)f32_bf16(f3.w);
    *(bf16x8*)&Vb[r][s * 16] = t0;
    *(bf16x8*)&Vb[r][s * 16 + 8] = t1;
  }
  __syncthreads();
#pragma unroll
  for (int jj = 0; jj < 4; ++jj) {
    int p = jj * 256 + tid;
    int d = p >> 3, cb = p & 7;
    bf16x8 g;
#pragma unroll
    for (int e = 0; e < 8; ++e) g[e] = (short)Vb[cb * 8 + e][d];
    *(bf16x8*)(vtg + (size_t)h * 262144 + (size_t)d * 2048 + c0 + cb * 8) = g;
  }
}

// ---------------- Stage 2: masked causal flash attention (bf16 MFMA) ----------------
template <bool PRE>
__global__ __launch_bounds__(256) void attn_kernel(const float* __restrict__ q,
                                                   const float* __restrict__ kk,
                                                   const float* __restrict__ vv,
                                                   const u16* __restrict__ kbf,
                                                   const u16* __restrict__ vtg,
                                                   const u64* __restrict__ vbits,
                                                   const u64* __restrict__ sbits,
                                                   float* __restrict__ out) {
  int bid = blockIdx.x;
  int logical = (bid & 7) * 128 + (bid >> 3);  // 4 heads per XCD
  int h = logical >> 5;
  int qt = 31 - (logical & 31);                // heavy q-tiles first
  int tid = threadIdx.x;
  int wave = tid >> 6, lane = tid & 63;
  int grp = lane >> 4, ln = lane & 15;

  __shared__ u16 Ks[64 * 128];
  __shared__ u16 Vt[128 * 64];
  __shared__ u16 Ps[4][1152];  // per-wave 16 x 72
  __shared__ u64 vmw[32];
  __shared__ u64 smp[34];

  if (tid < 32) vmw[tid] = vbits[h * 32 + tid];
  else if (tid < 64) smp[tid - 32] = sbits[h * 32 + (tid - 32)];
  else if (tid < 66) smp[tid - 32] = 0ull;

  int q0 = qt * 64 + wave * 16;
  bf16x8 qf[4];
  const float* qrow = q + ((size_t)h * S_LEN + q0 + ln) * D_DIM;
#pragma unroll
  for (int ks = 0; ks < 4; ++ks) {
    const float* p = qrow + ks * 32 + grp * 8;
    float4 a = *(const float4*)p;
    float4 b = *(const float4*)(p + 4);
    bf16x8 f;
    f[0] = (short)f32_bf16(a.x * SCALE_F); f[1] = (short)f32_bf16(a.y * SCALE_F);
    f[2] = (short)f32_bf16(a.z * SCALE_F); f[3] = (short)f32_bf16(a.w * SCALE_F);
    f[4] = (short)f32_bf16(b.x * SCALE_F); f[5] = (short)f32_bf16(b.y * SCALE_F);
    f[6] = (short)f32_bf16(b.z * SCALE_F); f[7] = (short)f32_bf16(b.w * SCALE_F);
    qf[ks] = f;
  }
  f32x4 of[8];
#pragma unroll
  for (int i = 0; i < 8; ++i) of[i] = (f32x4){0.f, 0.f, 0.f, 0.f};
  float mr[4] = {-1e30f, -1e30f, -1e30f, -1e30f};
  float ls[4] = {0.f, 0.f, 0.f, 0.f};

  const u16* kb2 = PRE ? (kbf + (size_t)h * 262144) : nullptr;
  const u16* vb2 = PRE ? (vtg + (size_t)h * 262144) : nullptr;
  const float* kfb = kk + (size_t)h * S_LEN * D_DIM;
  const float* vfb = vv + (size_t)h * S_LEN * D_DIM;
  int ntiles = qt + 1;

  bf16x8 kst[4], vst[4];
  // T14 prologue: issue tile-0 loads
  if constexpr (PRE) {
#pragma unroll
    for (int j = 0; j < 4; ++j) {
      int p = j * 256 + tid;
      kst[j] = *(const bf16x8*)(kb2 + (size_t)(p >> 4) * 128 + (p & 15) * 8);
      vst[j] = *(const bf16x8*)(vb2 + (size_t)(p >> 3) * 2048 + (p & 7) * 8);
    }
  }

  for (int t = 0; t < ntiles; ++t) {
    int c0 = t * 64;
    __syncthreads();
    if constexpr (PRE) {
      // write staged regs -> LDS (XOR colblock swizzle)
#pragma unroll
      for (int j = 0; j < 4; ++j) {
        int p = j * 256 + tid;
        int r = p >> 4, pb = p & 15;
        *(bf16x8*)&Ks[r * 128 + ((pb ^ (r & 15)) << 3)] = kst[j];
        int d = p >> 3, pb2 = p & 7;
        *(bf16x8*)&Vt[d * 64 + ((pb2 ^ (d & 7)) << 3)] = vst[j];
      }
      if (t + 1 < ntiles) {
        int c1 = (t + 1) * 64;
#pragma unroll
        for (int j = 0; j < 4; ++j) {
          int p = j * 256 + tid;
          kst[j] = *(const bf16x8*)(kb2 + (size_t)(c1 + (p >> 4)) * 128 + (p & 15) * 8);
          vst[j] = *(const bf16x8*)(vb2 + (size_t)(p >> 3) * 2048 + c1 + (p & 7) * 8);
        }
      }
    } else {
      // in-kernel f32 -> bf16 staging
      for (int i = tid; i < 512; i += 256) {
        int r = i >> 3, s = i & 7;
        const float* srcp = kfb + (size_t)(c0 + r) * D_DIM + s * 16;
        float4 f0 = *(const float4*)(srcp);
        float4 f1 = *(const float4*)(srcp + 4);
        float4 f2 = *(const float4*)(srcp + 8);
        float4 f3 = *(const float4*)(srcp + 12);
        bf16x8 t0, t1;
        t0[0] = (short)f32_bf16(f0.x); t0[1] = (short)f32_bf16(f0.y);
        t0[2] = (short)f32_bf16(f0.z); t0[3] = (short)f32_bf16(f0.w);
        t0[4] = (short)f32_bf16(f1.x); t0[5] = (short)f32_bf16(f1.y);
        t0[6] = (short)f32_bf16(f1.z); t0[7] = (short)f32_bf16(f1.w);
        t1[0] = (short)f32_bf16(f2.x); t1[1] = (short)f32_bf16(f2.y);
        t1[2] = (short)f32_bf16(f2.z); t1[3] = (short)f32_bf16(f2.w);
        t1[4] = (short)f32_bf16(f3.x); t1[5] = (short)f32_bf16(f3.y);
        t1[6] = (short)f32_bf16(f3.z); t1[7] = (short)f32_bf16(f3.w);
        int cb0 = s * 2, cb1 = s * 2 + 1;
        *(bf16x8*)&Ks[r * 128 + ((cb0 ^ (r & 15)) << 3)] = t0;
        *(bf16x8*)&Ks[r * 128 + ((cb1 ^ (r & 15)) << 3)] = t1;
      }
      for (int i = tid; i < 512; i += 256) {
        int r = i >> 3, s = i & 7;
        const float* srcp = vfb + (size_t)(c0 + r) * D_DIM + s * 16;
#pragma unroll
        for (int x = 0; x < 16; x += 4) {
          float4 f4 = *(const float4*)(srcp + x);
          int d0 = s * 16 + x;
          float vals[4] = {f4.x, f4.y, f4.z, f4.w};
#pragma unroll
          for (int y = 0; y < 4; ++y) {
            int d = d0 + y;
            Vt[d * 64 + (((r >> 3) ^ (d & 7)) << 3) + (r & 7)] = f32_bf16(vals[y]);
          }
        }
      }
    }
    __syncthreads();

    // QK^T
    f32x4 sfr[4];
#pragma unroll
    for (int nb = 0; nb < 4; ++nb) {
      f32x4 acc = (f32x4){0.f, 0.f, 0.f, 0.f};
#pragma unroll
      for (int ks = 0; ks < 4; ++ks) {
        bf16x8 kf = *(const bf16x8*)&Ks[(nb * 16 + ln) * 128 + (((ks * 4 + grp) ^ ln) << 3)];
        acc = __builtin_amdgcn_mfma_f32_16x16x32_bf16(qf[ks], kf, acc, 0, 0, 0);
      }
      sfr[nb] = acc;
    }
    // mask
    int Cthr = (q0 + grp * 4) - (c0 + ln);  // d at (j=0, nb=0)
    if (t == qt) {
      // diagonal tile: all d in [0,63] are slash-kept -> causal only
#pragma unroll
      for (int nb = 0; nb < 4; ++nb)
#pragma unroll
        for (int j = 0; j < 4; ++j)
          sfr[nb][j] = (Cthr + j - 16 * nb >= 0) ? sfr[nb][j] : -1e30f;
    } else {
      int b = Cthr - 48;
      int w0i = b >> 6;
      int sh = b & 63;
      u64 lo = (w0i >= 0) ? smp[w0i] : 0ull;
      u64 hi = smp[w0i + 1];
      u64 W = (sh == 0) ? lo : ((lo >> sh) | (hi << (64 - sh)));
      u64 vword = vmw[c0 >> 6];
#pragma unroll
      for (int nb = 0; nb < 4; ++nb) {
        u32 vbit = (u32)(vword >> (nb * 16 + ln)) & 1u;
#pragma unroll
        for (int j = 0; j < 4; ++j) {
          u32 sbit = (u32)(W >> (48 + j - 16 * nb)) & 1u;
          bool keep = (Cthr + j - 16 * nb >= 0) && ((vbit | sbit) != 0u);
          sfr[nb][j] = keep ? sfr[nb][j] : -1e30f;
        }
      }
    }
    // row max
    f32x4 tm = sfr[0];
#pragma unroll
    for (int nb = 1; nb < 4; ++nb)
#pragma unroll
      for (int j = 0; j < 4; ++j) tm[j] = fmaxf(tm[j], sfr[nb][j]);
#pragma unroll
    for (int mk = 1; mk <= 8; mk <<= 1)
#pragma unroll
      for (int j = 0; j < 4; ++j) tm[j] = fmaxf(tm[j], __shfl_xor(tm[j], mk, 64));
    float ex[4];
#pragma unroll
    for (int j = 0; j < 4; ++j) {
      float mn = fmaxf(mr[j], tm[j]);
      ex[j] = __expf(mr[j] - mn);
      mr[j] = mn;
      ls[j] *= ex[j];
    }
#pragma unroll
    for (int db = 0; db < 8; ++db)
#pragma unroll
      for (int j = 0; j < 4; ++j) of[db][j] *= ex[j];
    float rs[4] = {0.f, 0.f, 0.f, 0.f};
#pragma unroll
    for (int nb = 0; nb < 4; ++nb)
#pragma unroll
      for (int j = 0; j < 4; ++j) {
        float p = __expf(sfr[nb][j] - mr[j]);
        rs[j] += p;
        Ps[wave][(grp * 4 + j) * 72 + nb * 16 + ln] = (u16)((__float_as_uint(p) + 0x8000u) >> 16);
      }
#pragma unroll
    for (int mk = 1; mk <= 8; mk <<= 1)
#pragma unroll
      for (int j = 0; j < 4; ++j) rs[j] += __shfl_xor(rs[j], mk, 64);
#pragma unroll
    for (int j = 0; j < 4; ++j) ls[j] += rs[j];
    // PV
#pragma unroll
    for (int ks = 0; ks < 2; ++ks) {
      bf16x8 pa = *(const bf16x8*)&Ps[wave][ln * 72 + ks * 32 + grp * 8];
#pragma unroll
      for (int db = 0; db < 8; ++db) {
        int d = db * 16 + ln;
        bf16x8 vf = *(const bf16x8*)&Vt[d * 64 + ((((ks << 2) | grp) ^ (ln & 7)) << 3)];
        of[db] = __builtin_amdgcn_mfma_f32_16x16x32_bf16(pa, vf, of[db], 0, 0, 0);
      }
    }
  }
  // epilogue
  float inv[4];
#pragma unroll
  for (int j = 0; j < 4; ++j) inv[j] = 1.f / ls[j];
  float* ob = out + ((size_t)h * S_LEN + q0) * D_DIM;
#pragma unroll
  for (int db = 0; db < 8; ++db)
#pragma unroll
    for (int j = 0; j < 4; ++j)
      ob[(size_t)(grp * 4 + j) * D_DIM + db * 16 + ln] = of[db][j] * inv[j];
}

extern "C" void kernel_launch(void* const* d_in, const int* in_sizes, int n_in,
                              void* d_out, int out_size, void* d_ws, size_t ws_size,
                              hipStream_t stream) {
  const float* q = (const float*)d_in[0];
  const float* k = (const float*)d_in[1];
  const float* v = (const float*)d_in[2];
  float* out = (float*)d_out;
  // d_out scratch layout (floats): scores [0,4194304), partials [4194304,5242880),
  // vert [5242880,+65536), slash [5308416,+65536). All overwritten by attn.
  float* scores = out;
  float* part = out + 4194304;
  float* vert = out + 5242880;
  float* slash = out + 5308416;
  u64* vbits = (u64*)d_ws;
  u64* sbits = vbits + 1024;
  const size_t PRE_NEED = 16384 + 2ull * 16777216;
  bool pre = ws_size >= PRE_NEED;
  u16* kbf = (u16*)((char*)d_ws + 16384);
  u16* vtg = kbf + 8388608;

  if (pre) {
    convk_kernel<<<4096, 256, 0, stream>>>(k, kbf);
    convv_kernel<<<dim3(32, 32), 256, 0, stream>>>(v, vtg);
  }
  est_kernel<<<dim3(32, 32), 256, 0, stream>>>(q, k, scores);
  soft_partial_kernel<<<dim3(32, 8), 256, 0, stream>>>(scores, part);
  soft_reduce_kernel<<<dim3(32, 2), 256, 0, stream>>>(part, vert, slash);
  topk_kernel<<<dim3(32, 2), 256, 0, stream>>>(vert, slash, vbits, sbits);
  if (pre)
    attn_kernel<true><<<1024, 256, 0, stream>>>(q, k, v, kbf, vtg, vbits, sbits, out);
  else
    attn_kernel<false><<<1024, 256, 0, stream>>>(q, k, v, kbf, vtg, vbits, sbits, out);
}